// Round 4
// baseline (469.791 us; speedup 1.0000x reference)
//
#include <hip/hip_runtime.h>
#include <stdint.h>

#define MM 8192
#define NN 4096
#define KK 4096
#define BM 256
#define BN 256
#define BK 64
#define NT (KK / BK)   // 64 K-tiles

typedef __attribute__((ext_vector_type(8))) short short8;
typedef __attribute__((ext_vector_type(4))) float floatx4;
typedef int int4a __attribute__((ext_vector_type(4), aligned(4)));  // 4B-aligned 16B load

// fp32 -> bf16 round-to-nearest-even
__device__ inline unsigned short f2bf(float f) {
    unsigned int u = __float_as_uint(f);
    u += 0x7FFFu + ((u >> 16) & 1u);
    return (unsigned short)(u >> 16);
}

// Convert x [8192,4096] fp32 -> bf16, 8 elems/thread, coalesced.
__global__ void prep_x_kernel(const float* __restrict__ x, unsigned short* __restrict__ xb) {
    size_t i = (size_t)blockIdx.x * 256 + threadIdx.x;
    const float4* x4 = (const float4*)x;
    float4 v0 = x4[i * 2];
    float4 v1 = x4[i * 2 + 1];
    ushort4 o0, o1;
    o0.x = f2bf(v0.x); o0.y = f2bf(v0.y); o0.z = f2bf(v0.z); o0.w = f2bf(v0.w);
    o1.x = f2bf(v1.x); o1.y = f2bf(v1.y); o1.z = f2bf(v1.z); o1.w = f2bf(v1.w);
    *(ushort4*)(xb + i * 8)     = o0;
    *(ushort4*)(xb + i * 8 + 4) = o1;
}

// vals (8191 fp32) -> two bf16 copies: vlo[i]=vals[i], vhi[i]=vals[i+1].
__global__ void prep_vals_kernel(const float* __restrict__ vals,
                                 unsigned short* __restrict__ vlo,
                                 unsigned short* __restrict__ vhi) {
    int i = blockIdx.x * 256 + threadIdx.x;
    if (i < KK + NN - 1) {
        unsigned short s = f2bf(vals[i]);
        vlo[i] = s;
        if (i > 0) vhi[i - 1] = s;
    }
}

#define GLOAD_LDS16(g, l)                                              \
    __builtin_amdgcn_global_load_lds(                                  \
        (__attribute__((address_space(1))) void*)(g),                  \
        (__attribute__((address_space(3))) void*)(l), 16, 0, 0)

// 256x256 tile, 8 waves (2Mx4N), 4-phase/K-tile counted-vmcnt schedule (T3+T4+T5).
// A-only LDS staging (4 x 32KB rotating buffers, XOR-8 swizzle, depth-2 prefetch);
// B (Toeplitz) comes from L1-resident vals copies, prefetched 1 tile ahead into
// ping-pong register sets. Raw s_barrier everywhere; vmcnt(12) once per K-tile.
// R4 change: MFMA16 loop order kh->ii->j (was ii->j->kh). kh-innermost made
// every acc[i][j] update a distance-1 RAW chain (issue 4.85cy, latency ~20cy
// -> pipe stalls; predicted util 2*4.85/~23 = 42% == measured 41.5%).
// kh-outer gives dependency distance 8 (39cy > latency, fully pipelined).
__global__ __launch_bounds__(512, 2) void gemm_kernel(
        const unsigned short* __restrict__ A,
        const unsigned short* __restrict__ vlo,
        const unsigned short* __restrict__ vhi,
        float* __restrict__ C) {
    __shared__ unsigned short ldsA[4][BM * BK];   // 4 x 32 KB = 128 KB

    const int tid  = threadIdx.x;
    const int lane = tid & 63;
    const int w    = tid >> 6;            // 0..7
    const int n0 = blockIdx.x * BN;
    const int m0 = blockIdx.y * BM;

    const int quad = lane >> 4;           // 0..3 (MFMA k-group)
    const int l16  = lane & 15;
    const int wm   = (w >> 2) * 128;      // wave row: 2 waves in M
    const int wn   = (w & 3) * 64;        // wave col: 4 waves in N

    // ---- A staging: wave w stages rows [w*32, w*32+32), 4 GLL of 8 rows each.
    // Lane l -> row (l>>3), slot (l&7); slot s of row r holds global chunk s^(r&7).
    const int lr8 = lane >> 3;
    const int cg  = (lane & 7) ^ (lr8 & 7);
    const unsigned short* aSrc = A + (size_t)(m0 + w * 32 + lr8) * KK + cg * 8;
    const int sBase = (w * 32) * BK;

    // ---- B pointers: idx = 4095 - (n0+wn+l16+j*16) + quad*8 (+k). Dual copy
    // (vlo/vhi) makes every even element offset 4B-aligned for dwordx4 loads.
    const unsigned short* bptr[4];
#pragma unroll
    for (int j = 0; j < 4; ++j) {
        int idx0 = (NN - 1) - (n0 + wn + l16) - j * 16 + quad * 8;
        bptr[j] = (idx0 & 1) ? (vhi + (idx0 - 1)) : (vlo + idx0);
    }

    floatx4 acc[8][4] = {};
    short8 b0r[8], b1r[8];                // ping-pong B fragment sets (tile parity)

#define STAGE1(BI, T, G)                                               \
    GLOAD_LDS16(aSrc + (size_t)(G) * 8 * KK + (size_t)(T) * BK,        \
                &ldsA[BI][sBase + (G) * 8 * BK])

#define LOADB(DST, T)                                                  \
    do {                                                               \
        _Pragma("unroll")                                              \
        for (int j = 0; j < 4; ++j) {                                  \
            _Pragma("unroll")                                          \
            for (int kh = 0; kh < 2; ++kh) {                           \
                int4a t_ = *(const int4a*)(bptr[j] + (size_t)(T) * BK + kh * 32); \
                __builtin_memcpy(&(DST)[j * 2 + kh], &t_, 16);         \
            }                                                          \
        }                                                              \
    } while (0)

#define AFRAG(AF, BI, P)                                               \
    do {                                                               \
        _Pragma("unroll")                                              \
        for (int ii = 0; ii < 2; ++ii) {                               \
            _Pragma("unroll")                                          \
            for (int kh = 0; kh < 2; ++kh)                             \
                (AF)[ii * 2 + kh] = *(const short8*)&ldsA[BI][         \
                    (wm + (2 * (P) + ii) * 16 + l16) * BK +            \
                    (((kh * 4 + quad) ^ (l16 & 7)) * 8)];              \
        }                                                              \
    } while (0)

// kh OUTER: dependent acc updates are 8 MFMAs apart (pipelined), not adjacent.
#define MFMA16(AF, BS, P)                                              \
    do {                                                               \
        _Pragma("unroll")                                              \
        for (int kh = 0; kh < 2; ++kh) {                               \
            _Pragma("unroll")                                          \
            for (int ii = 0; ii < 2; ++ii) {                           \
                _Pragma("unroll")                                      \
                for (int j = 0; j < 4; ++j)                            \
                    acc[2 * (P) + ii][j] =                             \
                        __builtin_amdgcn_mfma_f32_16x16x32_bf16(       \
                            (AF)[ii * 2 + kh], (BS)[j * 2 + kh],       \
                            acc[2 * (P) + ii][j], 0, 0, 0);            \
            }                                                          \
        }                                                              \
    } while (0)

#define SB()    __builtin_amdgcn_s_barrier()
#define PRIO(x) __builtin_amdgcn_s_setprio(x)
#define WAITV(N) asm volatile("s_waitcnt vmcnt(" #N ")" ::: "memory")

    // ---- prologue: GLL(0), b(0), GLL(1); wait tile0 landed (12 newer in flight)
#pragma unroll
    for (int g = 0; g < 4; ++g) STAGE1(0, 0, g);
    LOADB(b0r, 0);
#pragma unroll
    for (int g = 0; g < 4; ++g) STAGE1(1, 1, g);
    WAITV(12);
    SB();

    // Tile t reads buf[t&3]; stages tile t+2 into buf[(t+2)&3] (freed at t-2's
    // end); loads b(t+1) in phase 0. End-of-tile WAITV(12) = all GLL(t+1) done
    // (newer: 8 b(t+1) + 4 GLL(t+2) stay in flight). 2 raw barriers per phase
    // keep the 2 waves/SIMD in alternating ds_read/MFMA roles; setprio(1)
    // keeps the matrix pipe fed (T5).
#define TILE(BI, T, BCUR, BNXT, DOB, DOST, LW)                         \
    do {                                                               \
        short8 af_[4];                                                 \
        AFRAG(af_, BI, 0);                                             \
        if (DOB) LOADB(BNXT, (T) + 1);                                 \
        if (DOST) STAGE1(((BI) + 2) & 3, (T) + 2, 0);                  \
        SB(); PRIO(1); MFMA16(af_, BCUR, 0); PRIO(0); SB();            \
        AFRAG(af_, BI, 1);                                             \
        if (DOST) STAGE1(((BI) + 2) & 3, (T) + 2, 1);                  \
        SB(); PRIO(1); MFMA16(af_, BCUR, 1); PRIO(0); SB();            \
        AFRAG(af_, BI, 2);                                             \
        if (DOST) STAGE1(((BI) + 2) & 3, (T) + 2, 2);                  \
        SB(); PRIO(1); MFMA16(af_, BCUR, 2); PRIO(0); SB();            \
        AFRAG(af_, BI, 3);                                             \
        if (DOST) STAGE1(((BI) + 2) & 3, (T) + 2, 3);                  \
        SB(); PRIO(1); MFMA16(af_, BCUR, 3); PRIO(0);                  \
        LW; SB();                                                      \
    } while (0)

    for (int u = 0; u < 15; ++u) {
        const int t = u * 4;
        TILE(0, t + 0, b0r, b1r, 1, 1, WAITV(12));
        TILE(1, t + 1, b1r, b0r, 1, 1, WAITV(12));
        TILE(2, t + 2, b0r, b1r, 1, 1, WAITV(12));
        TILE(3, t + 3, b1r, b0r, 1, 1, WAITV(12));
    }
    // Peeled drain: tiles 60..63 (stages 62,63 still issued; then taper waits)
    TILE(0, 60, b0r, b1r, 1, 1, WAITV(12));
    TILE(1, 61, b1r, b0r, 1, 1, WAITV(12));
    TILE(2, 62, b0r, b1r, 1, 0, WAITV(8));
    TILE(3, 63, b1r, b0r, 0, 0, (void)0);

    // Epilogue: C/D layout col = lane&15, row = quad*4 + reg (m89-verified)
    float* cW = C + (size_t)(m0 + wm) * NN + (n0 + wn);
#pragma unroll
    for (int i = 0; i < 8; ++i) {
#pragma unroll
        for (int j = 0; j < 4; ++j) {
            float* cp = cW + (size_t)(i * 16 + quad * 4) * NN + j * 16 + l16;
#pragma unroll
            for (int r = 0; r < 4; ++r)
                cp[(size_t)r * NN] = acc[i][j][r];
        }
    }
#undef TILE
#undef STAGE1
#undef LOADB
#undef AFRAG
#undef MFMA16
}

extern "C" void kernel_launch(void* const* d_in, const int* in_sizes, int n_in,
                              void* d_out, int out_size, void* d_ws, size_t ws_size,
                              hipStream_t stream) {
    const float* x    = (const float*)d_in[0];
    const float* vals = (const float*)d_in[1];
    float* out = (float*)d_out;

    unsigned short* xb  = (unsigned short*)d_ws;          // 67.1 MB
    unsigned short* vlo = xb + (size_t)MM * KK;
    unsigned short* vhi = vlo + 16384;

    prep_x_kernel<<<MM * KK / 8 / 256, 256, 0, stream>>>(x, xb);
    prep_vals_kernel<<<(KK + NN - 1 + 255) / 256, 256, 0, stream>>>(vals, vlo, vhi);

    dim3 grid(NN / BN, MM / BM);
    gemm_kernel<<<grid, 512, 0, stream>>>(xb, vlo, vhi, out);
}

// Round 5
// 453.679 us; speedup vs baseline: 1.0355x; 1.0355x over previous
//
#include <hip/hip_runtime.h>
#include <stdint.h>

#define MM 8192
#define NN 4096
#define KK 4096
#define BM 256
#define BN 256
#define BK 64
#define NT (KK / BK)   // 64 K-tiles

typedef __attribute__((ext_vector_type(8))) short short8;
typedef __attribute__((ext_vector_type(4))) float floatx4;
typedef int int4a __attribute__((ext_vector_type(4), aligned(4)));  // 4B-aligned 16B load

// fp32 -> bf16 round-to-nearest-even
__device__ inline unsigned short f2bf(float f) {
    unsigned int u = __float_as_uint(f);
    u += 0x7FFFu + ((u >> 16) & 1u);
    return (unsigned short)(u >> 16);
}

// Convert x [8192,4096] fp32 -> bf16, 8 elems/thread, coalesced.
__global__ void prep_x_kernel(const float* __restrict__ x, unsigned short* __restrict__ xb) {
    size_t i = (size_t)blockIdx.x * 256 + threadIdx.x;
    const float4* x4 = (const float4*)x;
    float4 v0 = x4[i * 2];
    float4 v1 = x4[i * 2 + 1];
    ushort4 o0, o1;
    o0.x = f2bf(v0.x); o0.y = f2bf(v0.y); o0.z = f2bf(v0.z); o0.w = f2bf(v0.w);
    o1.x = f2bf(v1.x); o1.y = f2bf(v1.y); o1.z = f2bf(v1.z); o1.w = f2bf(v1.w);
    *(ushort4*)(xb + i * 8)     = o0;
    *(ushort4*)(xb + i * 8 + 4) = o1;
}

// vals (8191 fp32) -> two bf16 copies: vlo[i]=vals[i], vhi[i]=vals[i+1].
__global__ void prep_vals_kernel(const float* __restrict__ vals,
                                 unsigned short* __restrict__ vlo,
                                 unsigned short* __restrict__ vhi) {
    int i = blockIdx.x * 256 + threadIdx.x;
    if (i < KK + NN - 1) {
        unsigned short s = f2bf(vals[i]);
        vlo[i] = s;
        if (i > 0) vhi[i - 1] = s;
    }
}

#define GLOAD_LDS16(g, l)                                              \
    __builtin_amdgcn_global_load_lds(                                  \
        (__attribute__((address_space(1))) void*)(g),                  \
        (__attribute__((address_space(3))) void*)(l), 16, 0, 0)

// 256x256 tile, 8 waves (2Mx4N). R5: BARRIER-LIGHT schedule — exactly ONE
// raw s_barrier + WAITV(12) per K-tile (was 8 barriers/tile). R4 analysis:
// phase = 1350cy, MFMA = 620cy, LDS = 384cy; the per-phase barrier pairs
// serialized LDS reads against MFMA (lockstep) -> MfmaUtil stuck at 42%.
// Correctness needs only the tile-boundary barrier: buf[BI] is overwritten
// by GLL(t+4), >=2 barriers after its readers; WAITV(12) before SB drains
// GLL(t+1) (12 newer ops: 8 LOADB(t+1) + 4 GLL(t+2) stay in flight).
// A-fragments double-buffered (afA/afB); AFRAG(p+1) precedes MFMA16(p) so
// the compiler hides ds_read latency under the MFMA clusters (4 ds_read per
// 16 MFMA -> LDS fits under MFMA, unlike m97's 8:16 which was LDS-bound).
__global__ __launch_bounds__(512, 2) void gemm_kernel(
        const unsigned short* __restrict__ A,
        const unsigned short* __restrict__ vlo,
        const unsigned short* __restrict__ vhi,
        float* __restrict__ C) {
    __shared__ unsigned short ldsA[4][BM * BK];   // 4 x 32 KB = 128 KB

    const int tid  = threadIdx.x;
    const int lane = tid & 63;
    const int w    = tid >> 6;            // 0..7
    const int n0 = blockIdx.x * BN;
    const int m0 = blockIdx.y * BM;

    const int quad = lane >> 4;           // 0..3 (MFMA k-group)
    const int l16  = lane & 15;
    const int wm   = (w >> 2) * 128;      // wave row: 2 waves in M
    const int wn   = (w & 3) * 64;        // wave col: 4 waves in N

    // ---- A staging: wave w stages rows [w*32, w*32+32), 4 GLL of 8 rows each.
    // Lane l -> row (l>>3), slot (l&7); slot s of row r holds global chunk s^(r&7).
    const int lr8 = lane >> 3;
    const int cg  = (lane & 7) ^ (lr8 & 7);
    const unsigned short* aSrc = A + (size_t)(m0 + w * 32 + lr8) * KK + cg * 8;
    const int sBase = (w * 32) * BK;

    // ---- B pointers: idx = 4095 - (n0+wn+l16+j*16) + quad*8 (+k). Dual copy
    // (vlo/vhi) makes every even element offset 4B-aligned for dwordx4 loads.
    const unsigned short* bptr[4];
#pragma unroll
    for (int j = 0; j < 4; ++j) {
        int idx0 = (NN - 1) - (n0 + wn + l16) - j * 16 + quad * 8;
        bptr[j] = (idx0 & 1) ? (vhi + (idx0 - 1)) : (vlo + idx0);
    }

    floatx4 acc[8][4] = {};
    short8 b0r[8], b1r[8];                // ping-pong B fragment sets (tile parity)
    short8 afA[4], afB[4];                // ping-pong A fragment sets (phase parity)

#define STAGE1(BI, T, G)                                               \
    GLOAD_LDS16(aSrc + (size_t)(G) * 8 * KK + (size_t)(T) * BK,        \
                &ldsA[BI][sBase + (G) * 8 * BK])

#define LOADB(DST, T)                                                  \
    do {                                                               \
        _Pragma("unroll")                                              \
        for (int j = 0; j < 4; ++j) {                                  \
            _Pragma("unroll")                                          \
            for (int kh = 0; kh < 2; ++kh) {                           \
                int4a t_ = *(const int4a*)(bptr[j] + (size_t)(T) * BK + kh * 32); \
                __builtin_memcpy(&(DST)[j * 2 + kh], &t_, 16);         \
            }                                                          \
        }                                                              \
    } while (0)

#define AFRAG(AF, BI, P)                                               \
    do {                                                               \
        _Pragma("unroll")                                              \
        for (int ii = 0; ii < 2; ++ii) {                               \
            _Pragma("unroll")                                          \
            for (int kh = 0; kh < 2; ++kh)                             \
                (AF)[ii * 2 + kh] = *(const short8*)&ldsA[BI][         \
                    (wm + (2 * (P) + ii) * 16 + l16) * BK +            \
                    (((kh * 4 + quad) ^ (l16 & 7)) * 8)];              \
        }                                                              \
    } while (0)

// kh OUTER: dependent acc updates are 8 MFMAs apart (pipelined), not adjacent.
#define MFMA16(AF, BS, P)                                              \
    do {                                                               \
        _Pragma("unroll")                                              \
        for (int kh = 0; kh < 2; ++kh) {                               \
            _Pragma("unroll")                                          \
            for (int ii = 0; ii < 2; ++ii) {                           \
                _Pragma("unroll")                                      \
                for (int j = 0; j < 4; ++j)                            \
                    acc[2 * (P) + ii][j] =                             \
                        __builtin_amdgcn_mfma_f32_16x16x32_bf16(       \
                            (AF)[ii * 2 + kh], (BS)[j * 2 + kh],       \
                            acc[2 * (P) + ii][j], 0, 0, 0);            \
            }                                                          \
        }                                                              \
    } while (0)

// Raw barrier with compile-time fences: no hardware waitcnt drain, but the
// compiler may not migrate LDS/global ops across it (GLL visibility after SB
// is guaranteed by each wave's WAITV before SB + the barrier itself).
#define SB()                                                           \
    do {                                                               \
        asm volatile("" ::: "memory");                                 \
        __builtin_amdgcn_s_barrier();                                  \
        asm volatile("" ::: "memory");                                 \
    } while (0)
#define PRIO(x) __builtin_amdgcn_s_setprio(x)
#define WAITV(N) asm volatile("s_waitcnt vmcnt(" #N ")" ::: "memory")

    // ---- prologue: GLL(0), b(0), GLL(1); wait tile0 landed (12 newer in flight)
#pragma unroll
    for (int g = 0; g < 4; ++g) STAGE1(0, 0, g);
    LOADB(b0r, 0);
#pragma unroll
    for (int g = 0; g < 4; ++g) STAGE1(1, 1, g);
    WAITV(12);
    SB();
    AFRAG(afA, 0, 0);   // tile 0 phase-0 frags

    // Tile t: reads buf[t&3]; stages tile t+2; loads b(t+1). No intra-tile
    // barriers — compiler pipelines ds_read(p+1) under MFMA(p). On entry afA
    // holds phase-0 frags; at tile end (after WAITV+SB) afA is reloaded with
    // next tile's phase-0 frags, then the last MFMA cluster runs.
#define TILE(BI, T, BCUR, BNXT, DOB, DOST, DONXT, LW)                  \
    do {                                                               \
        if (DOB) LOADB(BNXT, (T) + 1);                                 \
        AFRAG(afB, BI, 1);                                             \
        if (DOST) STAGE1(((BI) + 2) & 3, (T) + 2, 0);                  \
        PRIO(1); MFMA16(afA, BCUR, 0); PRIO(0);                        \
        AFRAG(afA, BI, 2);                                             \
        if (DOST) STAGE1(((BI) + 2) & 3, (T) + 2, 1);                  \
        PRIO(1); MFMA16(afB, BCUR, 1); PRIO(0);                        \
        AFRAG(afB, BI, 3);                                             \
        if (DOST) STAGE1(((BI) + 2) & 3, (T) + 2, 2);                  \
        PRIO(1); MFMA16(afA, BCUR, 2); PRIO(0);                        \
        if (DOST) STAGE1(((BI) + 2) & 3, (T) + 2, 3);                  \
        LW;                                                            \
        if (DONXT) { SB(); AFRAG(afA, ((BI) + 1) & 3, 0); }            \
        PRIO(1); MFMA16(afB, BCUR, 3); PRIO(0);                        \
    } while (0)

    for (int u = 0; u < 15; ++u) {
        const int t = u * 4;
        TILE(0, t + 0, b0r, b1r, 1, 1, 1, WAITV(12));
        TILE(1, t + 1, b1r, b0r, 1, 1, 1, WAITV(12));
        TILE(2, t + 2, b0r, b1r, 1, 1, 1, WAITV(12));
        TILE(3, t + 3, b1r, b0r, 1, 1, 1, WAITV(12));
    }
    // Peeled drain: tiles 60..63. 62 stages nothing beyond 63; WAITV(8)
    // drains GLL(63) (8 newer LOADB(63) in flight); 63 is compute-only.
    TILE(0, 60, b0r, b1r, 1, 1, 1, WAITV(12));
    TILE(1, 61, b1r, b0r, 1, 1, 1, WAITV(12));
    TILE(2, 62, b0r, b1r, 1, 0, 1, WAITV(8));
    TILE(3, 63, b1r, b0r, 0, 0, 0, (void)0);

    // Epilogue: C/D layout col = lane&15, row = quad*4 + reg (m89-verified)
    float* cW = C + (size_t)(m0 + wm) * NN + (n0 + wn);
#pragma unroll
    for (int i = 0; i < 8; ++i) {
#pragma unroll
        for (int j = 0; j < 4; ++j) {
            float* cp = cW + (size_t)(i * 16 + quad * 4) * NN + j * 16 + l16;
#pragma unroll
            for (int r = 0; r < 4; ++r)
                cp[(size_t)r * NN] = acc[i][j][r];
        }
    }
#undef TILE
#undef STAGE1
#undef LOADB
#undef AFRAG
#undef MFMA16
}

extern "C" void kernel_launch(void* const* d_in, const int* in_sizes, int n_in,
                              void* d_out, int out_size, void* d_ws, size_t ws_size,
                              hipStream_t stream) {
    const float* x    = (const float*)d_in[0];
    const float* vals = (const float*)d_in[1];
    float* out = (float*)d_out;

    unsigned short* xb  = (unsigned short*)d_ws;          // 67.1 MB
    unsigned short* vlo = xb + (size_t)MM * KK;
    unsigned short* vhi = vlo + 16384;

    prep_x_kernel<<<MM * KK / 8 / 256, 256, 0, stream>>>(x, xb);
    prep_vals_kernel<<<(KK + NN - 1 + 255) / 256, 256, 0, stream>>>(vals, vlo, vhi);

    dim3 grid(NN / BN, MM / BM);
    gemm_kernel<<<grid, 512, 0, stream>>>(xb, vlo, vhi, out);
}

// Round 6
// 432.909 us; speedup vs baseline: 1.0852x; 1.0480x over previous
//
#include <hip/hip_runtime.h>
#include <stdint.h>

#define MM 8192
#define NN 4096
#define KK 4096
#define BM 256
#define BN 256
#define BK 64

// B-window LDS geometry: 4 shift-copies (s=0..3), stride 4376 elems (8752B,
// = 547*16B; mod 128B = 48B -> arrays land 12 banks apart). 4352 elems staged.
#define BW_STRIDE 4376

typedef __attribute__((ext_vector_type(8))) short short8;
typedef __attribute__((ext_vector_type(4))) float floatx4;
typedef int int4a __attribute__((ext_vector_type(4), aligned(4)));  // 4B-aligned 16B load

// fp32 -> bf16 round-to-nearest-even
__device__ inline unsigned short f2bf(float f) {
    unsigned int u = __float_as_uint(f);
    u += 0x7FFFu + ((u >> 16) & 1u);
    return (unsigned short)(u >> 16);
}

// Convert x [8192,4096] fp32 -> bf16, 8 elems/thread, coalesced.
__global__ void prep_x_kernel(const float* __restrict__ x, unsigned short* __restrict__ xb) {
    size_t i = (size_t)blockIdx.x * 256 + threadIdx.x;
    const float4* x4 = (const float4*)x;
    float4 v0 = x4[i * 2];
    float4 v1 = x4[i * 2 + 1];
    ushort4 o0, o1;
    o0.x = f2bf(v0.x); o0.y = f2bf(v0.y); o0.z = f2bf(v0.z); o0.w = f2bf(v0.w);
    o1.x = f2bf(v1.x); o1.y = f2bf(v1.y); o1.z = f2bf(v1.z); o1.w = f2bf(v1.w);
    *(ushort4*)(xb + i * 8)     = o0;
    *(ushort4*)(xb + i * 8 + 4) = o1;
}

// vals (8191 fp32) -> two bf16 copies: vlo[i]=vals[i], vhi[i]=vals[i+1].
__global__ void prep_vals_kernel(const float* __restrict__ vals,
                                 unsigned short* __restrict__ vlo,
                                 unsigned short* __restrict__ vhi) {
    int i = blockIdx.x * 256 + threadIdx.x;
    if (i < KK + NN - 1) {
        unsigned short s = f2bf(vals[i]);
        vlo[i] = s;
        if (i > 0) vhi[i - 1] = s;
    }
}

#define GLOAD_LDS16(g, l)                                              \
    __builtin_amdgcn_global_load_lds(                                  \
        (__attribute__((address_space(1))) void*)(g),                  \
        (__attribute__((address_space(3))) void*)(l), 16, 0, 0)

// 256x256 tile, 8 waves (2Mx4N), one raw barrier + WAITV per K-tile (R5).
// R6: B moved OFF the vector-memory path. R5 accounting: tile=4875cy =
// MFMA 2480 + LDS-A 1540 + VALU 715 + B-via-L1 ~2050 (128KB/tile/CU of
// redundant frag loads at ~64B/cy) -> pipes nearly serial, L1-B is the
// biggest non-MFMA stream. The block's ENTIRE Toeplitz B operand is a
// 4.3K-elem vals window (8.7KB): stage 4 alignment-shifted bf16 copies
// (35KB LDS) once in the prologue; B-frags become 2x ds_read_b64 (8B
// aligned via shift-copy s=idx0&3; overlapping lane windows broadcast).
// vmem/tile is now just 4 GLLs -> WAITV(4). A-buffers 4->3 (mod-3
// rotation, depth-2 prefetch: writer(t+2) buffer (t+2)%3 != readers' t%3,
// (t+1)%3; its old readers (tile t-1) all passed the barrier ending t-1).
__global__ __launch_bounds__(512, 2) void gemm_kernel(
        const unsigned short* __restrict__ A,
        const unsigned short* __restrict__ vlo,
        const unsigned short* __restrict__ vhi,
        float* __restrict__ C) {
    __shared__ unsigned short ldsA[3][BM * BK];      // 3 x 32 KB = 96 KB
    __shared__ unsigned short ldsB[4 * BW_STRIDE];   // 35 KB B window copies

    const int tid  = threadIdx.x;
    const int lane = tid & 63;
    const int w    = tid >> 6;            // 0..7
    const int n0 = blockIdx.x * BN;
    const int m0 = blockIdx.y * BM;

    const int quad = lane >> 4;           // 0..3 (MFMA k-group)
    const int l16  = lane & 15;
    const int wm   = (w >> 2) * 128;      // wave row: 2 waves in M
    const int wn   = (w & 3) * 64;        // wave col: 4 waves in N

    // ---- A staging: wave w stages rows [w*32, w*32+32), 4 GLL of 8 rows each.
    // Lane l -> row (l>>3), slot (l&7); slot s of row r holds global chunk s^(r&7).
    const int lr8 = lane >> 3;
    const int cg  = (lane & 7) ^ (lr8 & 7);
    const unsigned short* aSrc = A + (size_t)(m0 + w * 32 + lr8) * KK + cg * 8;
    const int sBase = (w * 32) * BK;

    // ---- B window: idx0 = 4095-(n0+wn+l16)-j*16+quad*8; min over block = w0.
    // ldsB copy s holds vals[w0+s+i]; lane picks s=idx0&3 so its element
    // offset (idx0-s-w0)+k is = 0 mod 4 -> byte = 0 mod 8 (b64-aligned).
    // w0 = 3840-n0 is a multiple of 64, so idx0-s >= w0 (i >= 0).
    const int w0 = (NN - 1) - 255 - n0;   // 3840 - n0
    const unsigned short* bp[4];
#pragma unroll
    for (int j = 0; j < 4; ++j) {
        int idx0 = (NN - 1) - (n0 + wn + l16) - j * 16 + quad * 8;
        int s = idx0 & 3;
        bp[j] = ldsB + s * BW_STRIDE + (idx0 - s - w0);
    }

    floatx4 acc[8][4] = {};
    short8 b0r[8], b1r[8];                // ping-pong B fragment sets (tile parity)
    short8 afA[4], afB[4];                // ping-pong A fragment sets (phase parity)

#define STAGE1(BI, T, G)                                               \
    GLOAD_LDS16(aSrc + (size_t)(G) * 8 * KK + (size_t)(T) * BK,        \
                &ldsA[BI][sBase + (G) * 8 * BK])

// B-frag from the LDS window: two ds_read_b64 per frag (8B-aligned).
#define LOADB(DST, T)                                                  \
    do {                                                               \
        _Pragma("unroll")                                              \
        for (int j = 0; j < 4; ++j) {                                  \
            _Pragma("unroll")                                          \
            for (int kh = 0; kh < 2; ++kh) {                           \
                const unsigned short* p_ = bp[j] + (T) * BK + kh * 32; \
                uint2 lo_ = *(const uint2*)p_;                         \
                uint2 hi_ = *(const uint2*)(p_ + 4);                   \
                short8 f_;                                             \
                __builtin_memcpy(&f_, &lo_, 8);                        \
                __builtin_memcpy((char*)&f_ + 8, &hi_, 8);             \
                (DST)[j * 2 + kh] = f_;                                \
            }                                                          \
        }                                                              \
    } while (0)

#define AFRAG(AF, BI, P)                                               \
    do {                                                               \
        _Pragma("unroll")                                              \
        for (int ii = 0; ii < 2; ++ii) {                               \
            _Pragma("unroll")                                          \
            for (int kh = 0; kh < 2; ++kh)                             \
                (AF)[ii * 2 + kh] = *(const short8*)&ldsA[BI][         \
                    (wm + (2 * (P) + ii) * 16 + l16) * BK +            \
                    (((kh * 4 + quad) ^ (l16 & 7)) * 8)];              \
        }                                                              \
    } while (0)

// kh OUTER: dependent acc updates are 8 MFMAs apart (pipelined), not adjacent.
#define MFMA16(AF, BS, P)                                              \
    do {                                                               \
        _Pragma("unroll")                                              \
        for (int kh = 0; kh < 2; ++kh) {                               \
            _Pragma("unroll")                                          \
            for (int ii = 0; ii < 2; ++ii) {                           \
                _Pragma("unroll")                                      \
                for (int j = 0; j < 4; ++j)                            \
                    acc[2 * (P) + ii][j] =                             \
                        __builtin_amdgcn_mfma_f32_16x16x32_bf16(       \
                            (AF)[ii * 2 + kh], (BS)[j * 2 + kh],       \
                            acc[2 * (P) + ii][j], 0, 0, 0);            \
            }                                                          \
        }                                                              \
    } while (0)

#define SB()                                                           \
    do {                                                               \
        asm volatile("" ::: "memory");                                 \
        __builtin_amdgcn_s_barrier();                                  \
        asm volatile("" ::: "memory");                                 \
    } while (0)
#define PRIO(x) __builtin_amdgcn_s_setprio(x)
#define WAITV(N) asm volatile("s_waitcnt vmcnt(" #N ")" ::: "memory")

    // ---- prologue: stage B window copies (plain load + ds_write), GLL tiles
    // 0 and 1, then one full __syncthreads (vmcnt+lgkm drain, once).
    {
        const unsigned short* bsrc0 = vlo + w0;
        const unsigned short* bsrc1 = vhi + w0;
        const unsigned short* bsrc2 = vlo + w0 + 2;
        const unsigned short* bsrc3 = vhi + w0 + 2;
#pragma unroll
        for (int s = 0; s < 4; ++s) {
            const unsigned short* sp = (s == 0) ? bsrc0 : (s == 1) ? bsrc1
                                     : (s == 2) ? bsrc2 : bsrc3;
            unsigned short* dp = ldsB + s * BW_STRIDE;
            int4a v = *(const int4a*)(sp + (size_t)tid * 8);
            *(int4a*)(dp + tid * 8) = v;
            if (tid < 32) {
                int4a v2 = *(const int4a*)(sp + (size_t)(512 + tid) * 8);
                *(int4a*)(dp + (512 + tid) * 8) = v2;
            }
        }
    }
#pragma unroll
    for (int g = 0; g < 4; ++g) STAGE1(0, 0, g);
#pragma unroll
    for (int g = 0; g < 4; ++g) STAGE1(1, 1, g);
    __syncthreads();
    LOADB(b0r, 0);
    AFRAG(afA, 0, 0);   // tile 0 phase-0 frags

    // Tile t: reads buf t%3; stages t+2 into (t+2)%3; reads B(t+1) frags from
    // the static LDS window. vmem = 4 GLL/tile; WAITV(4) at tile end = GLL(t+1)
    // drained, GLL(t+2) (4 newer) stays in flight. One barrier per tile.
#define TILE(BI, BIN, BI2, T, BCUR, BNXT, DOB, DOST, DONXT, LW)        \
    do {                                                               \
        if (DOB) LOADB(BNXT, (T) + 1);                                 \
        AFRAG(afB, BI, 1);                                             \
        if (DOST) STAGE1(BI2, (T) + 2, 0);                             \
        PRIO(1); MFMA16(afA, BCUR, 0); PRIO(0);                        \
        AFRAG(afA, BI, 2);                                             \
        if (DOST) STAGE1(BI2, (T) + 2, 1);                             \
        PRIO(1); MFMA16(afB, BCUR, 1); PRIO(0);                        \
        AFRAG(afB, BI, 3);                                             \
        if (DOST) STAGE1(BI2, (T) + 2, 2);                             \
        PRIO(1); MFMA16(afA, BCUR, 2); PRIO(0);                        \
        if (DOST) STAGE1(BI2, (T) + 2, 3);                             \
        LW;                                                            \
        if (DONXT) { SB(); AFRAG(afA, BIN, 0); }                       \
        PRIO(1); MFMA16(afB, BCUR, 3); PRIO(0);                        \
    } while (0)

    // 6-tile unroll keeps both the mod-3 buffer index and the b-set parity
    // compile-time constant per call position. Tiles 0..59.
    for (int v = 0; v < 10; ++v) {
        const int t = v * 6;
        TILE(0, 1, 2, t + 0, b0r, b1r, 1, 1, 1, WAITV(4));
        TILE(1, 2, 0, t + 1, b1r, b0r, 1, 1, 1, WAITV(4));
        TILE(2, 0, 1, t + 2, b0r, b1r, 1, 1, 1, WAITV(4));
        TILE(0, 1, 2, t + 3, b1r, b0r, 1, 1, 1, WAITV(4));
        TILE(1, 2, 0, t + 4, b0r, b1r, 1, 1, 1, WAITV(4));
        TILE(2, 0, 1, t + 5, b1r, b0r, 1, 1, 1, WAITV(4));
    }
    // Peeled drain: 60 stages 62, 61 stages 63, 62 stages nothing (WAITV(0)
    // waits GLL(63), last prefetch), 63 compute-only.
    TILE(0, 1, 2, 60, b0r, b1r, 1, 1, 1, WAITV(4));
    TILE(1, 2, 0, 61, b1r, b0r, 1, 1, 1, WAITV(4));
    TILE(2, 0, 1, 62, b0r, b1r, 1, 0, 1, WAITV(0));
    TILE(0, 1, 2, 63, b1r, b0r, 0, 0, 0, (void)0);

    // Epilogue: C/D layout col = lane&15, row = quad*4 + reg (m89-verified)
    float* cW = C + (size_t)(m0 + wm) * NN + (n0 + wn);
#pragma unroll
    for (int i = 0; i < 8; ++i) {
#pragma unroll
        for (int j = 0; j < 4; ++j) {
            float* cp = cW + (size_t)(i * 16 + quad * 4) * NN + j * 16 + l16;
#pragma unroll
            for (int r = 0; r < 4; ++r)
                cp[(size_t)r * NN] = acc[i][j][r];
        }
    }
#undef TILE
#undef STAGE1
#undef LOADB
#undef AFRAG
#undef MFMA16
}

extern "C" void kernel_launch(void* const* d_in, const int* in_sizes, int n_in,
                              void* d_out, int out_size, void* d_ws, size_t ws_size,
                              hipStream_t stream) {
    const float* x    = (const float*)d_in[0];
    const float* vals = (const float*)d_in[1];
    float* out = (float*)d_out;

    unsigned short* xb  = (unsigned short*)d_ws;          // 67.1 MB
    unsigned short* vlo = xb + (size_t)MM * KK;
    unsigned short* vhi = vlo + 16384;

    prep_x_kernel<<<MM * KK / 8 / 256, 256, 0, stream>>>(x, xb);
    prep_vals_kernel<<<(KK + NN - 1 + 255) / 256, 256, 0, stream>>>(vals, vlo, vhi);

    dim3 grid(NN / BN, MM / BM);
    gemm_kernel<<<grid, 512, 0, stream>>>(xb, vlo, vhi, out);
}

// Round 7
// 422.794 us; speedup vs baseline: 1.1112x; 1.0239x over previous
//
#include <hip/hip_runtime.h>
#include <stdint.h>

#define MM 8192
#define NN 4096
#define KK 4096
#define BM 256
#define BN 256
#define BK 64

typedef __attribute__((ext_vector_type(8))) short short8;
typedef __attribute__((ext_vector_type(4))) float floatx4;
typedef int int4a __attribute__((ext_vector_type(4), aligned(4)));  // 4B-aligned 16B load

// fp32 -> bf16 round-to-nearest-even
__device__ inline unsigned short f2bf(float f) {
    unsigned int u = __float_as_uint(f);
    u += 0x7FFFu + ((u >> 16) & 1u);
    return (unsigned short)(u >> 16);
}

// Convert x [8192,4096] fp32 -> bf16, 8 elems/thread, coalesced.
__global__ void prep_x_kernel(const float* __restrict__ x, unsigned short* __restrict__ xb) {
    size_t i = (size_t)blockIdx.x * 256 + threadIdx.x;
    const float4* x4 = (const float4*)x;
    float4 v0 = x4[i * 2];
    float4 v1 = x4[i * 2 + 1];
    ushort4 o0, o1;
    o0.x = f2bf(v0.x); o0.y = f2bf(v0.y); o0.z = f2bf(v0.z); o0.w = f2bf(v0.w);
    o1.x = f2bf(v1.x); o1.y = f2bf(v1.y); o1.z = f2bf(v1.z); o1.w = f2bf(v1.w);
    *(ushort4*)(xb + i * 8)     = o0;
    *(ushort4*)(xb + i * 8 + 4) = o1;
}

// vals (8191 fp32) -> two bf16 copies: vlo[i]=vals[i], vhi[i]=vals[i+1].
__global__ void prep_vals_kernel(const float* __restrict__ vals,
                                 unsigned short* __restrict__ vlo,
                                 unsigned short* __restrict__ vhi) {
    int i = blockIdx.x * 256 + threadIdx.x;
    if (i < KK + NN - 1) {
        unsigned short s = f2bf(vals[i]);
        vlo[i] = s;
        if (i > 0) vhi[i - 1] = s;
    }
}

#define GLOAD_LDS16(g, l)                                              \
    __builtin_amdgcn_global_load_lds(                                  \
        (__attribute__((address_space(1))) void*)(g),                  \
        (__attribute__((address_space(3))) void*)(l), 16, 0, 0)

// 256x256 tile, 8 waves (2Mx4N), one raw barrier + WAITV(4) per K-tile.
// R7: B window re-laid INTERLEAVED. R6's copy-major layout (4 shift-copies
// at s*STRIDE) scattered a wave's 16 l16-lanes across 4 copies at a 12-bank
// relative offset -> SQ_LDS_BANK_CONFLICT = 1.26e7 (~8% of runtime).
// New layout: F8[d] = vals[w0+d .. w0+d+3] at byte addr 8d (uint2; same
// 34.8KB, same data, different address map). A B-frag = F8[d] + F8[d+4],
// two 8B-aligned ds_read_b64. Per wave instr: d = base - l16 + 8*quad ->
// 16 consecutive entries per quad = 32 consecutive dwords = every bank
// exactly once; across quads 128 accesses hit 80 unique dwords (~2.5/bank,
// broadcast-heavy) -> ~conflict-free. Everything else identical to R6.
__global__ __launch_bounds__(512, 2) void gemm_kernel(
        const unsigned short* __restrict__ A,
        const unsigned short* __restrict__ vlo,
        const unsigned short* __restrict__ vhi,
        float* __restrict__ C) {
    __shared__ unsigned short ldsA[3][BM * BK];      // 3 x 32 KB = 96 KB
    __shared__ uint2 ldsB[4352];                     // 34.8 KB interleaved F8

    const int tid  = threadIdx.x;
    const int lane = tid & 63;
    const int w    = tid >> 6;            // 0..7
    const int n0 = blockIdx.x * BN;
    const int m0 = blockIdx.y * BM;

    const int quad = lane >> 4;           // 0..3 (MFMA k-group)
    const int l16  = lane & 15;
    const int wm   = (w >> 2) * 128;      // wave row: 2 waves in M
    const int wn   = (w & 3) * 64;        // wave col: 4 waves in N

    // ---- A staging: wave w stages rows [w*32, w*32+32), 4 GLL of 8 rows each.
    // Lane l -> row (l>>3), slot (l&7); slot s of row r holds global chunk s^(r&7).
    const int lr8 = lane >> 3;
    const int cg  = (lane & 7) ^ (lr8 & 7);
    const unsigned short* aSrc = A + (size_t)(m0 + w * 32 + lr8) * KK + cg * 8;
    const int sBase = (w * 32) * BK;

    // ---- B window entry offsets: idx0 = 4095-(n0+wn+l16)-16j+8quad;
    // entry d = idx0 - w0 (0..279); frag k adds T*64+kh*32 to d.
    const int w0 = (NN - 1) - 255 - n0;   // 3840 - n0 (even)
    int bofs[4];
#pragma unroll
    for (int j = 0; j < 4; ++j) {
        int idx0 = (NN - 1) - (n0 + wn + l16) - j * 16 + quad * 8;
        bofs[j] = idx0 - w0;
    }

    floatx4 acc[8][4] = {};
    short8 b0r[8], b1r[8];                // ping-pong B fragment sets (tile parity)
    short8 afA[4], afB[4];                // ping-pong A fragment sets (phase parity)

#define STAGE1(BI, T, G)                                               \
    GLOAD_LDS16(aSrc + (size_t)(G) * 8 * KK + (size_t)(T) * BK,        \
                &ldsA[BI][sBase + (G) * 8 * BK])

// B-frag from interleaved window: entries d_ (elems 0..3) and d_+4 (4..7).
#define LOADB(DST, T)                                                  \
    do {                                                               \
        _Pragma("unroll")                                              \
        for (int j = 0; j < 4; ++j) {                                  \
            _Pragma("unroll")                                          \
            for (int kh = 0; kh < 2; ++kh) {                           \
                int d_ = bofs[j] + (T) * BK + kh * 32;                 \
                uint2 lo_ = ldsB[d_];                                  \
                uint2 hi_ = ldsB[d_ + 4];                              \
                short8 f_;                                             \
                __builtin_memcpy(&f_, &lo_, 8);                        \
                __builtin_memcpy((char*)&f_ + 8, &hi_, 8);             \
                (DST)[j * 2 + kh] = f_;                                \
            }                                                          \
        }                                                              \
    } while (0)

#define AFRAG(AF, BI, P)                                               \
    do {                                                               \
        _Pragma("unroll")                                              \
        for (int ii = 0; ii < 2; ++ii) {                               \
            _Pragma("unroll")                                          \
            for (int kh = 0; kh < 2; ++kh)                             \
                (AF)[ii * 2 + kh] = *(const short8*)&ldsA[BI][         \
                    (wm + (2 * (P) + ii) * 16 + l16) * BK +            \
                    (((kh * 4 + quad) ^ (l16 & 7)) * 8)];              \
        }                                                              \
    } while (0)

// kh OUTER: dependent acc updates are 8 MFMAs apart (pipelined), not adjacent.
#define MFMA16(AF, BS, P)                                              \
    do {                                                               \
        _Pragma("unroll")                                              \
        for (int kh = 0; kh < 2; ++kh) {                               \
            _Pragma("unroll")                                          \
            for (int ii = 0; ii < 2; ++ii) {                           \
                _Pragma("unroll")                                      \
                for (int j = 0; j < 4; ++j)                            \
                    acc[2 * (P) + ii][j] =                             \
                        __builtin_amdgcn_mfma_f32_16x16x32_bf16(       \
                            (AF)[ii * 2 + kh], (BS)[j * 2 + kh],       \
                            acc[2 * (P) + ii][j], 0, 0, 0);            \
            }                                                          \
        }                                                              \
    } while (0)

#define SB()                                                           \
    do {                                                               \
        asm volatile("" ::: "memory");                                 \
        __builtin_amdgcn_s_barrier();                                  \
        asm volatile("" ::: "memory");                                 \
    } while (0)
#define PRIO(x) __builtin_amdgcn_s_setprio(x)
#define WAITV(N) asm volatile("s_waitcnt vmcnt(" #N ")" ::: "memory")

    // ---- prologue: build interleaved B window (9 iters/thread max), GLL
    // tiles 0 and 1, then one full __syncthreads (only full drain in kernel).
    {
        const uint* vl32 = (const uint*)(vlo + w0);   // w0 even -> 4B-aligned
        const uint* vh32 = (const uint*)(vhi + w0);
        for (int d = tid; d < 4352; d += 512) {
            const uint* s_ = (d & 1) ? (vh32 + (d >> 1)) : (vl32 + (d >> 1));
            uint2 e_;
            e_.x = s_[0];
            e_.y = s_[1];
            ldsB[d] = e_;
        }
    }
#pragma unroll
    for (int g = 0; g < 4; ++g) STAGE1(0, 0, g);
#pragma unroll
    for (int g = 0; g < 4; ++g) STAGE1(1, 1, g);
    __syncthreads();
    LOADB(b0r, 0);
    AFRAG(afA, 0, 0);   // tile 0 phase-0 frags

    // Tile t: reads buf t%3; stages t+2 into (t+2)%3; reads B(t+1) frags from
    // the static LDS window. vmem = 4 GLL/tile; WAITV(4) at tile end = GLL(t+1)
    // drained, GLL(t+2) (4 newer) stays in flight. One barrier per tile.
#define TILE(BI, BIN, BI2, T, BCUR, BNXT, DOB, DOST, DONXT, LW)        \
    do {                                                               \
        if (DOB) LOADB(BNXT, (T) + 1);                                 \
        AFRAG(afB, BI, 1);                                             \
        if (DOST) STAGE1(BI2, (T) + 2, 0);                             \
        PRIO(1); MFMA16(afA, BCUR, 0); PRIO(0);                        \
        AFRAG(afA, BI, 2);                                             \
        if (DOST) STAGE1(BI2, (T) + 2, 1);                             \
        PRIO(1); MFMA16(afB, BCUR, 1); PRIO(0);                        \
        AFRAG(afB, BI, 3);                                             \
        if (DOST) STAGE1(BI2, (T) + 2, 2);                             \
        PRIO(1); MFMA16(afA, BCUR, 2); PRIO(0);                        \
        if (DOST) STAGE1(BI2, (T) + 2, 3);                             \
        LW;                                                            \
        if (DONXT) { SB(); AFRAG(afA, BIN, 0); }                       \
        PRIO(1); MFMA16(afB, BCUR, 3); PRIO(0);                        \
    } while (0)

    // 6-tile unroll keeps both the mod-3 buffer index and the b-set parity
    // compile-time constant per call position. Tiles 0..59.
    for (int v = 0; v < 10; ++v) {
        const int t = v * 6;
        TILE(0, 1, 2, t + 0, b0r, b1r, 1, 1, 1, WAITV(4));
        TILE(1, 2, 0, t + 1, b1r, b0r, 1, 1, 1, WAITV(4));
        TILE(2, 0, 1, t + 2, b0r, b1r, 1, 1, 1, WAITV(4));
        TILE(0, 1, 2, t + 3, b1r, b0r, 1, 1, 1, WAITV(4));
        TILE(1, 2, 0, t + 4, b0r, b1r, 1, 1, 1, WAITV(4));
        TILE(2, 0, 1, t + 5, b1r, b0r, 1, 1, 1, WAITV(4));
    }
    // Peeled drain: 60 stages 62, 61 stages 63, 62 stages nothing (WAITV(0)
    // waits GLL(63), last prefetch), 63 compute-only.
    TILE(0, 1, 2, 60, b0r, b1r, 1, 1, 1, WAITV(4));
    TILE(1, 2, 0, 61, b1r, b0r, 1, 1, 1, WAITV(4));
    TILE(2, 0, 1, 62, b0r, b1r, 1, 0, 1, WAITV(0));
    TILE(0, 1, 2, 63, b1r, b0r, 0, 0, 0, (void)0);

    // Epilogue: C/D layout col = lane&15, row = quad*4 + reg (m89-verified)
    float* cW = C + (size_t)(m0 + wm) * NN + (n0 + wn);
#pragma unroll
    for (int i = 0; i < 8; ++i) {
#pragma unroll
        for (int j = 0; j < 4; ++j) {
            float* cp = cW + (size_t)(i * 16 + quad * 4) * NN + j * 16 + l16;
#pragma unroll
            for (int r = 0; r < 4; ++r)
                cp[(size_t)r * NN] = acc[i][j][r];
        }
    }
#undef TILE
#undef STAGE1
#undef LOADB
#undef AFRAG
#undef MFMA16
}

extern "C" void kernel_launch(void* const* d_in, const int* in_sizes, int n_in,
                              void* d_out, int out_size, void* d_ws, size_t ws_size,
                              hipStream_t stream) {
    const float* x    = (const float*)d_in[0];
    const float* vals = (const float*)d_in[1];
    float* out = (float*)d_out;

    unsigned short* xb  = (unsigned short*)d_ws;          // 67.1 MB
    unsigned short* vlo = xb + (size_t)MM * KK;
    unsigned short* vhi = vlo + 16384;

    prep_x_kernel<<<MM * KK / 8 / 256, 256, 0, stream>>>(x, xb);
    prep_vals_kernel<<<(KK + NN - 1 + 255) / 256, 256, 0, stream>>>(vals, vlo, vhi);

    dim3 grid(NN / BN, MM / BM);
    gemm_kernel<<<grid, 512, 0, stream>>>(xb, vlo, vhi, out);
}